// Round 3
// baseline (1079.902 us; speedup 1.0000x reference)
//
#include <hip/hip_runtime.h>
#include <cstdio>

#define NTOK 8192
#define DIM 1024
#define HID 2048
#define NE 8
#define NPAIR (NTOK * 2)

typedef __attribute__((ext_vector_type(8))) short bf16x8;
typedef __attribute__((ext_vector_type(4))) float f32x4;

typedef const __attribute__((address_space(1))) void* gas_ptr;
typedef __attribute__((address_space(3))) void* las_ptr;

__device__ __forceinline__ void async16(const void* g, void* s) {
  // direct global->LDS, 16B per lane; LDS dest = wave-uniform base + lane*16
  __builtin_amdgcn_global_load_lds((gas_ptr)g, (las_ptr)s, 16, 0, 0);
}

__device__ __forceinline__ unsigned short f2bf(float f) {
  unsigned int u = __float_as_uint(f);
  u = (u + 0x7fff + ((u >> 16) & 1)) >> 16;  // RNE
  return (unsigned short)u;
}

// LDS tiles are [row][64 bf16] = 128B rows. Physical 16B-chunk of (row r,
// logical chunk c) is c ^ (r&7) -> fragment reads spread across all 8 bank
// groups (2-way aliasing only, free on gfx950). Staging lane loads global
// chunk (slot&7)^(row&7) since its LDS slot chunk is fixed.

// ---------------------------------------------------------------------------
// prep: w1[e][d][h] -> w1bt[e][h][d] (bf16), w2 same, w3[e][h][d] -> w3bt[e][d][h]
// ---------------------------------------------------------------------------
__global__ __launch_bounds__(256) void prep_kernel(
    const float* __restrict__ w1, const float* __restrict__ w2,
    const float* __restrict__ w3, unsigned short* __restrict__ w1bt,
    unsigned short* __restrict__ w2bt, unsigned short* __restrict__ w3bt) {
  const int z = blockIdx.y;
  const int m = z >> 3, e = z & 7;
  int R, C;
  const float* in;
  unsigned short* outp;
  if (m == 0)      { R = DIM; C = HID; in = w1; outp = w1bt; }
  else if (m == 1) { R = DIM; C = HID; in = w2; outp = w2bt; }
  else             { R = HID; C = DIM; in = w3; outp = w3bt; }
  in += (size_t)e * DIM * HID;
  outp += (size_t)e * DIM * HID;

  const int tilesx = C >> 5;
  const int c0 = (blockIdx.x % tilesx) * 32;
  const int r0 = (blockIdx.x / tilesx) * 32;

  __shared__ float tile[32][33];
  const int c = threadIdx.x & 31, rr = threadIdx.x >> 5;
#pragma unroll
  for (int i = 0; i < 4; i++) {
    const int r = rr + i * 8;
    tile[r][c] = in[(size_t)(r0 + r) * C + c0 + c];
  }
  __syncthreads();
#pragma unroll
  for (int i = 0; i < 4; i++) {
    const int cc2 = rr + i * 8;  // column of original = row of output
    outp[(size_t)(c0 + cc2) * R + r0 + c] = f2bf(tile[c][cc2]);
  }
}

// ---------------------------------------------------------------------------
// gating: 1 wave per token. logits -> softmax -> top2 -> routes, scores.
// ---------------------------------------------------------------------------
__global__ __launch_bounds__(256) void gate_kernel(
    const float* __restrict__ x, const float* __restrict__ gw,
    const float* __restrict__ gb, unsigned short* __restrict__ xb,
    float* __restrict__ scores, int* __restrict__ route_e,
    float* __restrict__ route_w, int* __restrict__ ctrl) {
  __shared__ float sgw[DIM * NE];  // 32 KB
  const int tid = threadIdx.x;
  const float4* g4 = (const float4*)gw;
  float4* s4 = (float4*)sgw;
#pragma unroll
  for (int i = 0; i < 8; i++) s4[i * 256 + tid] = g4[i * 256 + tid];
  __syncthreads();

  const int wv = tid >> 6, lane = tid & 63;
  const int t = blockIdx.x * 4 + wv;
  float acc[NE] = {0.f, 0.f, 0.f, 0.f, 0.f, 0.f, 0.f, 0.f};
  const float4* x4 = (const float4*)(x + (size_t)t * DIM);
#pragma unroll
  for (int i = 0; i < 4; i++) {
    const float4 xv = x4[i * 64 + lane];
    const int d0 = (i * 64 + lane) * 4;
    ushort4 xbv;
    xbv.x = f2bf(xv.x); xbv.y = f2bf(xv.y);
    xbv.z = f2bf(xv.z); xbv.w = f2bf(xv.w);
    *(ushort4*)(xb + (size_t)t * DIM + d0) = xbv;
#pragma unroll
    for (int e = 0; e < NE; e++)
      acc[e] += xv.x * sgw[d0 * NE + e] + xv.y * sgw[(d0 + 1) * NE + e] +
                xv.z * sgw[(d0 + 2) * NE + e] + xv.w * sgw[(d0 + 3) * NE + e];
  }
#pragma unroll
  for (int e = 0; e < NE; e++)
#pragma unroll
    for (int s = 32; s; s >>= 1) acc[e] += __shfl_xor(acc[e], s, 64);

  if (lane == 0) {
    float l[NE], m = -1e30f;
#pragma unroll
    for (int e = 0; e < NE; e++) { l[e] = acc[e] + gb[e]; m = fmaxf(m, l[e]); }
    float p[NE], sum = 0.f;
#pragma unroll
    for (int e = 0; e < NE; e++) { p[e] = __expf(l[e] - m); sum += p[e]; }
    const float inv = 1.f / sum;
    float s[NE];
#pragma unroll
    for (int e = 0; e < NE; e++) { s[e] = p[e] * inv; scores[t * NE + e] = s[e]; }
    int i1 = 0;
    for (int e = 1; e < NE; e++) if (s[e] > s[i1]) i1 = e;
    int i2 = -1;
    for (int e = 0; e < NE; e++) {
      if (e == i1) continue;
      if (i2 < 0 || s[e] > s[i2]) i2 = e;
    }
    route_e[t * 2] = i1; route_e[t * 2 + 1] = i2;
    route_w[t * 2] = s[i1]; route_w[t * 2 + 1] = s[i2];
    atomicAdd(&ctrl[i1], 1);
    atomicAdd(&ctrl[i2], 1);
  }
}

// ---------------------------------------------------------------------------
// finalize: usage -> lb_loss (d_out tail), prefix offsets, init cursors.
// ---------------------------------------------------------------------------
__global__ void finalize_kernel(const float* __restrict__ scores,
                                int* __restrict__ ctrl,
                                float* __restrict__ out_lb) {
  __shared__ float red[1024];
  const int tid = threadIdx.x;
  const int e = tid & 7, row = tid >> 3;
  float s = 0.f;
  for (int i = 0; i < 64; i++) s += scores[(size_t)(row + i * 128) * NE + e];
  red[tid] = s;
  for (int st = 512; st >= 8; st >>= 1) {
    __syncthreads();
    if (tid < st) red[tid] += red[tid + st];
  }
  __syncthreads();
  if (tid == 0) {
    float lb = 0.f;
    for (int ee = 0; ee < NE; ee++) {
      const float u = red[ee] * (1.f / 8192.f);
      lb -= u * __logf(u + 1e-9f);
    }
    *out_lb = lb;
    int o = 0;
    for (int ee = 0; ee < NE; ee++) {
      ctrl[8 + ee] = o;
      ctrl[17 + ee] = o;
      o += ctrl[ee];
    }
    ctrl[16] = o;
  }
}

// ---------------------------------------------------------------------------
// scatter: build per-expert compacted token lists
// ---------------------------------------------------------------------------
__global__ void scatter_kernel(const int* __restrict__ route_e,
                               const float* __restrict__ route_w,
                               int* __restrict__ ctrl,
                               int* __restrict__ tok_list,
                               float* __restrict__ pair_w) {
  const int t = blockIdx.x * 256 + threadIdx.x;
  if (t >= NTOK) return;
#pragma unroll
  for (int k = 0; k < 2; k++) {
    const int e = route_e[t * 2 + k];
    const int p = atomicAdd(&ctrl[17 + e], 1);
    tok_list[p] = t;
    pair_w[p] = route_w[t * 2 + k] * 0.70710678118654752f;  // comb * 1/sqrt(2)
  }
}

// ---------------------------------------------------------------------------
// stage1: act = (X@W1 + b1) * silu(X@W2 + b2) for routed rows. bf16 out.
// grid (16, 64, 8), block 256. Tile 128 tokens x 128 hid, BK=64, 2x2 waves,
// each wave 64x64 sub-tile (4x4 acc grid). XOR-swizzled LDS.
// ---------------------------------------------------------------------------
__global__ __launch_bounds__(256) void stage1_kernel(
    const unsigned short* __restrict__ xb, const unsigned short* __restrict__ w1bt,
    const unsigned short* __restrict__ w2bt, const float* __restrict__ b1,
    const float* __restrict__ b2, const int* __restrict__ tok_list,
    const int* __restrict__ ctrl, unsigned short* __restrict__ act) {
  const int e = blockIdx.z;
  const int cnt = ctrl[e];
  const int ytile = blockIdx.y;
  if (ytile * 128 >= cnt) return;
  const int off = ctrl[8 + e];
  const int rows = min(128, cnt - ytile * 128);
  const int h0 = blockIdx.x * 128;

  __shared__ unsigned short sX[128 * 64];
  __shared__ unsigned short sW1[128 * 64];
  __shared__ unsigned short sW2[128 * 64];
  __shared__ int stok[128];

  const int tid = threadIdx.x;
  const int wv = tid >> 6, lane = tid & 63;

  if (tid < 128) stok[tid] = tok_list[off + ytile * 128 + min(tid, rows - 1)];
  __syncthreads();

  const int rr = tid >> 3;                      // staging row 0..31 (+32 per round)
  const int c8 = ((tid & 7) ^ (rr & 7)) * 8;    // swizzled chunk offset (shorts)
  const unsigned short* w1p = w1bt + (size_t)e * HID * DIM + (size_t)h0 * DIM;
  const unsigned short* w2p = w2bt + (size_t)e * HID * DIM + (size_t)h0 * DIM;
  const unsigned short* gx[4];
  const unsigned short* gw1[4];
  const unsigned short* gw2[4];
#pragma unroll
  for (int r = 0; r < 4; r++) {
    gx[r]  = xb + (size_t)stok[rr + r * 32] * DIM + c8;
    gw1[r] = w1p + (size_t)(rr + r * 32) * DIM + c8;
    gw2[r] = w2p + (size_t)(rr + r * 32) * DIM + c8;
  }

  f32x4 acc1[4][4], acc2[4][4];
#pragma unroll
  for (int i = 0; i < 4; i++)
#pragma unroll
    for (int j = 0; j < 4; j++) {
      acc1[i][j] = (f32x4){0.f, 0.f, 0.f, 0.f};
      acc2[i][j] = (f32x4){0.f, 0.f, 0.f, 0.f};
    }

  const int wr = wv >> 1, wc = wv & 1;
  const int l15 = lane & 15, q = lane >> 4, r7 = lane & 7;

  for (int k0 = 0; k0 < DIM; k0 += 64) {
#pragma unroll
    for (int r = 0; r < 4; r++) {
      async16(gx[r],  sX  + (r * 256 + wv * 64) * 8);
      async16(gw1[r], sW1 + (r * 256 + wv * 64) * 8);
      async16(gw2[r], sW2 + (r * 256 + wv * 64) * 8);
      gx[r] += 64; gw1[r] += 64; gw2[r] += 64;
    }
    __syncthreads();  // drains vmcnt: LDS tiles ready
#pragma unroll
    for (int kk = 0; kk < 2; kk++) {
      const int pch = ((kk * 4 + q) ^ r7) * 8;
      bf16x8 af[4], bfA[4], bfB[4];
#pragma unroll
      for (int i = 0; i < 4; i++)
        af[i] = *(const bf16x8*)(sX + (wr * 64 + i * 16 + l15) * 64 + pch);
#pragma unroll
      for (int j = 0; j < 4; j++) {
        bfA[j] = *(const bf16x8*)(sW1 + (wc * 64 + j * 16 + l15) * 64 + pch);
        bfB[j] = *(const bf16x8*)(sW2 + (wc * 64 + j * 16 + l15) * 64 + pch);
      }
#pragma unroll
      for (int i = 0; i < 4; i++)
#pragma unroll
        for (int j = 0; j < 4; j++) {
          acc1[i][j] =
              __builtin_amdgcn_mfma_f32_16x16x32_bf16(af[i], bfA[j], acc1[i][j], 0, 0, 0);
          acc2[i][j] =
              __builtin_amdgcn_mfma_f32_16x16x32_bf16(af[i], bfB[j], acc2[i][j], 0, 0, 0);
        }
    }
    __syncthreads();  // protect LDS before next stage
  }

#pragma unroll
  for (int i = 0; i < 4; i++) {
#pragma unroll
    for (int j = 0; j < 4; j++) {
      const int hcol = h0 + wc * 64 + j * 16 + l15;
      const float bb1 = b1[e * HID + hcol];
      const float bb2 = b2[e * HID + hcol];
#pragma unroll
      for (int rg = 0; rg < 4; rg++) {
        const int row = wr * 64 + i * 16 + q * 4 + rg;
        if (row < rows) {
          const float hv = acc1[i][j][rg] + bb1;
          const float gv = acc2[i][j][rg] + bb2;
          const float av = hv * (gv / (1.f + __expf(-gv)));
          act[(size_t)(off + ytile * 128 + row) * HID + hcol] = f2bf(av);
        }
      }
    }
  }
}

// ---------------------------------------------------------------------------
// stage2: out[tok] += comb/sqrt2 * (act @ W3 + b3). grid (8, 64, 8), block 256.
// Tile 128 rows x 128 dim, BK=64, 2x2 waves.
// ---------------------------------------------------------------------------
__global__ __launch_bounds__(256) void stage2_kernel(
    const unsigned short* __restrict__ act, const unsigned short* __restrict__ w3bt,
    const float* __restrict__ b3, const int* __restrict__ tok_list,
    const float* __restrict__ pair_w, const int* __restrict__ ctrl,
    float* __restrict__ out) {
  const int e = blockIdx.z;
  const int cnt = ctrl[e];
  const int ytile = blockIdx.y;
  if (ytile * 128 >= cnt) return;
  const int off = ctrl[8 + e];
  const int rows = min(128, cnt - ytile * 128);
  const int d0 = blockIdx.x * 128;
  const int rbase = off + ytile * 128;

  __shared__ unsigned short sA[128 * 64];
  __shared__ unsigned short sW[128 * 64];

  const int tid = threadIdx.x;
  const int wv = tid >> 6, lane = tid & 63;

  const int rr = tid >> 3;
  const int c8 = ((tid & 7) ^ (rr & 7)) * 8;
  const unsigned short* w3p = w3bt + (size_t)e * DIM * HID + (size_t)d0 * HID;
  const unsigned short* ga[4];
  const unsigned short* gw[4];
#pragma unroll
  for (int r = 0; r < 4; r++) {
    ga[r] = act + (size_t)(rbase + min(rr + r * 32, rows - 1)) * HID + c8;
    gw[r] = w3p + (size_t)(rr + r * 32) * HID + c8;
  }

  f32x4 acc[4][4];
#pragma unroll
  for (int i = 0; i < 4; i++)
#pragma unroll
    for (int j = 0; j < 4; j++) acc[i][j] = (f32x4){0.f, 0.f, 0.f, 0.f};

  const int wr = wv >> 1, wc = wv & 1;
  const int l15 = lane & 15, q = lane >> 4, r7 = lane & 7;

  for (int k0 = 0; k0 < HID; k0 += 64) {
#pragma unroll
    for (int r = 0; r < 4; r++) {
      async16(ga[r], sA + (r * 256 + wv * 64) * 8);
      async16(gw[r], sW + (r * 256 + wv * 64) * 8);
      ga[r] += 64; gw[r] += 64;
    }
    __syncthreads();
#pragma unroll
    for (int kk = 0; kk < 2; kk++) {
      const int pch = ((kk * 4 + q) ^ r7) * 8;
      bf16x8 af[4], bf[4];
#pragma unroll
      for (int i = 0; i < 4; i++)
        af[i] = *(const bf16x8*)(sA + (wr * 64 + i * 16 + l15) * 64 + pch);
#pragma unroll
      for (int j = 0; j < 4; j++)
        bf[j] = *(const bf16x8*)(sW + (wc * 64 + j * 16 + l15) * 64 + pch);
#pragma unroll
      for (int i = 0; i < 4; i++)
#pragma unroll
        for (int j = 0; j < 4; j++)
          acc[i][j] =
              __builtin_amdgcn_mfma_f32_16x16x32_bf16(af[i], bf[j], acc[i][j], 0, 0, 0);
    }
    __syncthreads();
  }

#pragma unroll
  for (int i = 0; i < 4; i++) {
#pragma unroll
    for (int rg = 0; rg < 4; rg++) {
      const int row = wr * 64 + i * 16 + q * 4 + rg;
      if (row < rows) {
        const int pr = rbase + row;
        const int tok = tok_list[pr];
        const float wt = pair_w[pr];
#pragma unroll
        for (int j = 0; j < 4; j++) {
          const int dcol = d0 + wc * 64 + j * 16 + l15;
          const float v = (acc[i][j][rg] + b3[e * DIM + dcol]) * wt;
          atomicAdd(out + (size_t)tok * DIM + dcol, v);
        }
      }
    }
  }
}

// ---------------------------------------------------------------------------
// workspace layout (bytes)
// ---------------------------------------------------------------------------
static const size_t SZ_XB  = (size_t)NTOK * DIM * 2;        // 16 MB
static const size_t SZ_W   = (size_t)NE * DIM * HID * 2;    // 32 MB each
static const size_t SZ_ACT = (size_t)NPAIR * HID * 2;       // 64 MB
static const size_t OFF_XB  = 0;
static const size_t OFF_W1  = OFF_XB + SZ_XB;
static const size_t OFF_W2  = OFF_W1 + SZ_W;
static const size_t OFF_W3  = OFF_W2 + SZ_W;
static const size_t OFF_ACT = OFF_W3 + SZ_W;
static const size_t OFF_SC  = OFF_ACT + SZ_ACT;
static const size_t OFF_RE  = OFF_SC + (size_t)NTOK * NE * 4;
static const size_t OFF_RW  = OFF_RE + (size_t)NPAIR * 4;
static const size_t OFF_TL  = OFF_RW + (size_t)NPAIR * 4;
static const size_t OFF_PW  = OFF_TL + (size_t)NPAIR * 4;
static const size_t OFF_CT  = OFF_PW + (size_t)NPAIR * 4;
static const size_t WS_NEED = OFF_CT + 128;

extern "C" void kernel_launch(void* const* d_in, const int* in_sizes, int n_in,
                              void* d_out, int out_size, void* d_ws, size_t ws_size,
                              hipStream_t stream) {
  const float* x      = (const float*)d_in[0];
  const float* gate_w = (const float*)d_in[1];
  const float* gate_b = (const float*)d_in[2];
  const float* w1     = (const float*)d_in[3];
  const float* b1     = (const float*)d_in[4];
  const float* w2     = (const float*)d_in[5];
  const float* b2     = (const float*)d_in[6];
  const float* w3     = (const float*)d_in[7];
  const float* b3     = (const float*)d_in[8];
  float* out = (float*)d_out;

  if (ws_size < WS_NEED) {
    fprintf(stderr, "kernel_launch: ws_size %zu < needed %zu\n", ws_size, WS_NEED);
    return;
  }

  char* ws = (char*)d_ws;
  unsigned short* xb   = (unsigned short*)(ws + OFF_XB);
  unsigned short* w1bt = (unsigned short*)(ws + OFF_W1);
  unsigned short* w2bt = (unsigned short*)(ws + OFF_W2);
  unsigned short* w3bt = (unsigned short*)(ws + OFF_W3);
  unsigned short* act  = (unsigned short*)(ws + OFF_ACT);
  float* scores        = (float*)(ws + OFF_SC);
  int* route_e         = (int*)(ws + OFF_RE);
  float* route_w       = (float*)(ws + OFF_RW);
  int* tok_list        = (int*)(ws + OFF_TL);
  float* pair_w        = (float*)(ws + OFF_PW);
  int* ctrl            = (int*)(ws + OFF_CT);

  hipMemsetAsync(d_out, 0, (size_t)out_size * sizeof(float), stream);
  hipMemsetAsync(ctrl, 0, 128, stream);

  prep_kernel<<<dim3(2048, 24), 256, 0, stream>>>(w1, w2, w3, w1bt, w2bt, w3bt);
  gate_kernel<<<2048, 256, 0, stream>>>(x, gate_w, gate_b, xb, scores, route_e,
                                        route_w, ctrl);
  finalize_kernel<<<1, 1024, 0, stream>>>(scores, ctrl, out + (out_size - 1));
  scatter_kernel<<<32, 256, 0, stream>>>(route_e, route_w, ctrl, tok_list, pair_w);
  stage1_kernel<<<dim3(16, 64, 8), 256, 0, stream>>>(xb, w1bt, w2bt, b1, b2,
                                                     tok_list, ctrl, act);
  stage2_kernel<<<dim3(8, 64, 8), 256, 0, stream>>>(act, w3bt, b3, tok_list,
                                                    pair_w, ctrl, out);
}

// Round 4
// 965.542 us; speedup vs baseline: 1.1184x; 1.1184x over previous
//
#include <hip/hip_runtime.h>
#include <cstdio>

#define NTOK 8192
#define DIM 1024
#define HID 2048
#define NE 8
#define NPAIR (NTOK * 2)

typedef __attribute__((ext_vector_type(8))) short bf16x8;
typedef __attribute__((ext_vector_type(4))) float f32x4;

typedef const __attribute__((address_space(1))) void* gas_ptr;
typedef __attribute__((address_space(3))) void* las_ptr;

__device__ __forceinline__ void async16(const void* g, void* s) {
  // direct global->LDS, 16B per lane; LDS dest = wave-uniform base + lane*16
  __builtin_amdgcn_global_load_lds((gas_ptr)g, (las_ptr)s, 16, 0, 0);
}

__device__ __forceinline__ unsigned short f2bf(float f) {
  unsigned int u = __float_as_uint(f);
  u = (u + 0x7fff + ((u >> 16) & 1)) >> 16;  // RNE
  return (unsigned short)u;
}

__device__ __forceinline__ float bf2f(unsigned short u) {
  return __uint_as_float((unsigned int)u << 16);
}

// LDS tiles are [row][64 bf16] = 128B rows. Physical 16B-chunk of (row r,
// logical chunk c) is c ^ (r&7) -> fragment reads spread across all 8 bank
// groups (2-way aliasing only, free on gfx950). Staging lane loads global
// chunk (slot&7)^(row&7) since its LDS slot chunk is fixed.
// All GEMMs: 128x128 tile, BK=64, 2x2 waves, single 4x4 f32x4 acc per wave
// (64 acc regs -> ~164 total, no spill; r3's dual-acc 128-reg tile spilled).

// ---------------------------------------------------------------------------
// prep: w1[e][d][h] -> w1bt[e][h][d] (bf16), w2 same, w3[e][h][d] -> w3bt[e][d][h]
// ---------------------------------------------------------------------------
__global__ __launch_bounds__(256) void prep_kernel(
    const float* __restrict__ w1, const float* __restrict__ w2,
    const float* __restrict__ w3, unsigned short* __restrict__ w1bt,
    unsigned short* __restrict__ w2bt, unsigned short* __restrict__ w3bt) {
  const int z = blockIdx.y;
  const int m = z >> 3, e = z & 7;
  int R, C;
  const float* in;
  unsigned short* outp;
  if (m == 0)      { R = DIM; C = HID; in = w1; outp = w1bt; }
  else if (m == 1) { R = DIM; C = HID; in = w2; outp = w2bt; }
  else             { R = HID; C = DIM; in = w3; outp = w3bt; }
  in += (size_t)e * DIM * HID;
  outp += (size_t)e * DIM * HID;

  const int tilesx = C >> 5;
  const int c0 = (blockIdx.x % tilesx) * 32;
  const int r0 = (blockIdx.x / tilesx) * 32;

  __shared__ float tile[32][33];
  const int c = threadIdx.x & 31, rr = threadIdx.x >> 5;
#pragma unroll
  for (int i = 0; i < 4; i++) {
    const int r = rr + i * 8;
    tile[r][c] = in[(size_t)(r0 + r) * C + c0 + c];
  }
  __syncthreads();
#pragma unroll
  for (int i = 0; i < 4; i++) {
    const int cc2 = rr + i * 8;  // column of original = row of output
    outp[(size_t)(c0 + cc2) * R + r0 + c] = f2bf(tile[c][cc2]);
  }
}

// ---------------------------------------------------------------------------
// gating: 1 wave per token. logits -> softmax -> top2 -> routes, scores.
// ---------------------------------------------------------------------------
__global__ __launch_bounds__(256) void gate_kernel(
    const float* __restrict__ x, const float* __restrict__ gw,
    const float* __restrict__ gb, unsigned short* __restrict__ xb,
    float* __restrict__ scores, int* __restrict__ route_e,
    float* __restrict__ route_w, int* __restrict__ ctrl) {
  __shared__ float sgw[DIM * NE];  // 32 KB
  const int tid = threadIdx.x;
  const float4* g4 = (const float4*)gw;
  float4* s4 = (float4*)sgw;
#pragma unroll
  for (int i = 0; i < 8; i++) s4[i * 256 + tid] = g4[i * 256 + tid];
  __syncthreads();

  const int wv = tid >> 6, lane = tid & 63;
  const int t = blockIdx.x * 4 + wv;
  float acc[NE] = {0.f, 0.f, 0.f, 0.f, 0.f, 0.f, 0.f, 0.f};
  const float4* x4 = (const float4*)(x + (size_t)t * DIM);
#pragma unroll
  for (int i = 0; i < 4; i++) {
    const float4 xv = x4[i * 64 + lane];
    const int d0 = (i * 64 + lane) * 4;
    ushort4 xbv;
    xbv.x = f2bf(xv.x); xbv.y = f2bf(xv.y);
    xbv.z = f2bf(xv.z); xbv.w = f2bf(xv.w);
    *(ushort4*)(xb + (size_t)t * DIM + d0) = xbv;
#pragma unroll
    for (int e = 0; e < NE; e++)
      acc[e] += xv.x * sgw[d0 * NE + e] + xv.y * sgw[(d0 + 1) * NE + e] +
                xv.z * sgw[(d0 + 2) * NE + e] + xv.w * sgw[(d0 + 3) * NE + e];
  }
#pragma unroll
  for (int e = 0; e < NE; e++)
#pragma unroll
    for (int s = 32; s; s >>= 1) acc[e] += __shfl_xor(acc[e], s, 64);

  if (lane == 0) {
    float l[NE], m = -1e30f;
#pragma unroll
    for (int e = 0; e < NE; e++) { l[e] = acc[e] + gb[e]; m = fmaxf(m, l[e]); }
    float p[NE], sum = 0.f;
#pragma unroll
    for (int e = 0; e < NE; e++) { p[e] = __expf(l[e] - m); sum += p[e]; }
    const float inv = 1.f / sum;
    float s[NE];
#pragma unroll
    for (int e = 0; e < NE; e++) { s[e] = p[e] * inv; scores[t * NE + e] = s[e]; }
    int i1 = 0;
    for (int e = 1; e < NE; e++) if (s[e] > s[i1]) i1 = e;
    int i2 = -1;
    for (int e = 0; e < NE; e++) {
      if (e == i1) continue;
      if (i2 < 0 || s[e] > s[i2]) i2 = e;
    }
    route_e[t * 2] = i1; route_e[t * 2 + 1] = i2;
    route_w[t * 2] = s[i1]; route_w[t * 2 + 1] = s[i2];
    atomicAdd(&ctrl[i1], 1);
    atomicAdd(&ctrl[i2], 1);
  }
}

// ---------------------------------------------------------------------------
// finalize: usage -> lb_loss (d_out tail), prefix offsets, init cursors.
// ---------------------------------------------------------------------------
__global__ void finalize_kernel(const float* __restrict__ scores,
                                int* __restrict__ ctrl,
                                float* __restrict__ out_lb) {
  __shared__ float red[1024];
  const int tid = threadIdx.x;
  const int e = tid & 7, row = tid >> 3;
  float s = 0.f;
  for (int i = 0; i < 64; i++) s += scores[(size_t)(row + i * 128) * NE + e];
  red[tid] = s;
  for (int st = 512; st >= 8; st >>= 1) {
    __syncthreads();
    if (tid < st) red[tid] += red[tid + st];
  }
  __syncthreads();
  if (tid == 0) {
    float lb = 0.f;
    for (int ee = 0; ee < NE; ee++) {
      const float u = red[ee] * (1.f / 8192.f);
      lb -= u * __logf(u + 1e-9f);
    }
    *out_lb = lb;
    int o = 0;
    for (int ee = 0; ee < NE; ee++) {
      ctrl[8 + ee] = o;
      ctrl[17 + ee] = o;
      o += ctrl[ee];
    }
    ctrl[16] = o;
  }
}

// ---------------------------------------------------------------------------
// scatter: build per-expert compacted token lists + inverse map pair_pos
// ---------------------------------------------------------------------------
__global__ void scatter_kernel(const int* __restrict__ route_e,
                               const float* __restrict__ route_w,
                               int* __restrict__ ctrl,
                               int* __restrict__ tok_list,
                               float* __restrict__ pair_w,
                               int* __restrict__ pair_pos) {
  const int t = blockIdx.x * 256 + threadIdx.x;
  if (t >= NTOK) return;
#pragma unroll
  for (int k = 0; k < 2; k++) {
    const int e = route_e[t * 2 + k];
    const int p = atomicAdd(&ctrl[17 + e], 1);
    tok_list[p] = t;
    pair_w[p] = route_w[t * 2 + k] * 0.70710678118654752f;  // comb * 1/sqrt(2)
    pair_pos[t * 2 + k] = p;
  }
}

// ---------------------------------------------------------------------------
// stage1a: h = X@W1 + b1 for routed rows -> act (bf16)
// grid (16, 64, 8), block 256. 128x128 tile, BK=64, 2x2 waves, single acc.
// ---------------------------------------------------------------------------
__global__ __launch_bounds__(256) void stage1a_kernel(
    const unsigned short* __restrict__ xb, const unsigned short* __restrict__ wbt,
    const float* __restrict__ b1, const int* __restrict__ tok_list,
    const int* __restrict__ ctrl, unsigned short* __restrict__ act) {
  const int e = blockIdx.z;
  const int cnt = ctrl[e];
  const int ytile = blockIdx.y;
  if (ytile * 128 >= cnt) return;
  const int off = ctrl[8 + e];
  const int rows = min(128, cnt - ytile * 128);
  const int h0 = blockIdx.x * 128;

  __shared__ unsigned short sX[128 * 64];
  __shared__ unsigned short sW[128 * 64];
  __shared__ int stok[128];

  const int tid = threadIdx.x;
  const int wv = tid >> 6, lane = tid & 63;

  if (tid < 128) stok[tid] = tok_list[off + ytile * 128 + min(tid, rows - 1)];
  __syncthreads();

  const int rr = tid >> 3;
  const int c8 = ((tid & 7) ^ (rr & 7)) * 8;  // swizzled chunk offset (shorts)
  const unsigned short* wp = wbt + (size_t)e * HID * DIM + (size_t)h0 * DIM;
  const unsigned short* gx[4];
  const unsigned short* gw[4];
#pragma unroll
  for (int r = 0; r < 4; r++) {
    gx[r] = xb + (size_t)stok[rr + r * 32] * DIM + c8;
    gw[r] = wp + (size_t)(rr + r * 32) * DIM + c8;
  }

  f32x4 acc[4][4];
#pragma unroll
  for (int i = 0; i < 4; i++)
#pragma unroll
    for (int j = 0; j < 4; j++) acc[i][j] = (f32x4){0.f, 0.f, 0.f, 0.f};

  const int wr = wv >> 1, wc = wv & 1;
  const int l15 = lane & 15, q = lane >> 4, r7 = lane & 7;

  for (int k0 = 0; k0 < DIM; k0 += 64) {
#pragma unroll
    for (int r = 0; r < 4; r++) {
      async16(gx[r], sX + (r * 256 + wv * 64) * 8);
      async16(gw[r], sW + (r * 256 + wv * 64) * 8);
      gx[r] += 64; gw[r] += 64;
    }
    __syncthreads();
#pragma unroll
    for (int kk = 0; kk < 2; kk++) {
      const int pch = ((kk * 4 + q) ^ r7) * 8;
      bf16x8 af[4], bf[4];
#pragma unroll
      for (int i = 0; i < 4; i++)
        af[i] = *(const bf16x8*)(sX + (wr * 64 + i * 16 + l15) * 64 + pch);
#pragma unroll
      for (int j = 0; j < 4; j++)
        bf[j] = *(const bf16x8*)(sW + (wc * 64 + j * 16 + l15) * 64 + pch);
#pragma unroll
      for (int i = 0; i < 4; i++)
#pragma unroll
        for (int j = 0; j < 4; j++)
          acc[i][j] =
              __builtin_amdgcn_mfma_f32_16x16x32_bf16(af[i], bf[j], acc[i][j], 0, 0, 0);
    }
    __syncthreads();
  }

#pragma unroll
  for (int i = 0; i < 4; i++)
#pragma unroll
    for (int j = 0; j < 4; j++) {
      const int hcol = h0 + wc * 64 + j * 16 + l15;
      const float bb = b1[e * HID + hcol];
#pragma unroll
      for (int rg = 0; rg < 4; rg++) {
        const int row = wr * 64 + i * 16 + q * 4 + rg;
        if (row < rows)
          act[(size_t)(off + ytile * 128 + row) * HID + hcol] = f2bf(acc[i][j][rg] + bb);
      }
    }
}

// ---------------------------------------------------------------------------
// stage1b: g = X@W2 + b2; act *= in-place: act = h * silu(g)
// ---------------------------------------------------------------------------
__global__ __launch_bounds__(256) void stage1b_kernel(
    const unsigned short* __restrict__ xb, const unsigned short* __restrict__ wbt,
    const float* __restrict__ b2, const int* __restrict__ tok_list,
    const int* __restrict__ ctrl, unsigned short* __restrict__ act) {
  const int e = blockIdx.z;
  const int cnt = ctrl[e];
  const int ytile = blockIdx.y;
  if (ytile * 128 >= cnt) return;
  const int off = ctrl[8 + e];
  const int rows = min(128, cnt - ytile * 128);
  const int h0 = blockIdx.x * 128;

  __shared__ unsigned short sX[128 * 64];
  __shared__ unsigned short sW[128 * 64];
  __shared__ int stok[128];

  const int tid = threadIdx.x;
  const int wv = tid >> 6, lane = tid & 63;

  if (tid < 128) stok[tid] = tok_list[off + ytile * 128 + min(tid, rows - 1)];
  __syncthreads();

  const int rr = tid >> 3;
  const int c8 = ((tid & 7) ^ (rr & 7)) * 8;
  const unsigned short* wp = wbt + (size_t)e * HID * DIM + (size_t)h0 * DIM;
  const unsigned short* gx[4];
  const unsigned short* gw[4];
#pragma unroll
  for (int r = 0; r < 4; r++) {
    gx[r] = xb + (size_t)stok[rr + r * 32] * DIM + c8;
    gw[r] = wp + (size_t)(rr + r * 32) * DIM + c8;
  }

  f32x4 acc[4][4];
#pragma unroll
  for (int i = 0; i < 4; i++)
#pragma unroll
    for (int j = 0; j < 4; j++) acc[i][j] = (f32x4){0.f, 0.f, 0.f, 0.f};

  const int wr = wv >> 1, wc = wv & 1;
  const int l15 = lane & 15, q = lane >> 4, r7 = lane & 7;

  for (int k0 = 0; k0 < DIM; k0 += 64) {
#pragma unroll
    for (int r = 0; r < 4; r++) {
      async16(gx[r], sX + (r * 256 + wv * 64) * 8);
      async16(gw[r], sW + (r * 256 + wv * 64) * 8);
      gx[r] += 64; gw[r] += 64;
    }
    __syncthreads();
#pragma unroll
    for (int kk = 0; kk < 2; kk++) {
      const int pch = ((kk * 4 + q) ^ r7) * 8;
      bf16x8 af[4], bf[4];
#pragma unroll
      for (int i = 0; i < 4; i++)
        af[i] = *(const bf16x8*)(sX + (wr * 64 + i * 16 + l15) * 64 + pch);
#pragma unroll
      for (int j = 0; j < 4; j++)
        bf[j] = *(const bf16x8*)(sW + (wc * 64 + j * 16 + l15) * 64 + pch);
#pragma unroll
      for (int i = 0; i < 4; i++)
#pragma unroll
        for (int j = 0; j < 4; j++)
          acc[i][j] =
              __builtin_amdgcn_mfma_f32_16x16x32_bf16(af[i], bf[j], acc[i][j], 0, 0, 0);
    }
    __syncthreads();
  }

#pragma unroll
  for (int i = 0; i < 4; i++)
#pragma unroll
    for (int j = 0; j < 4; j++) {
      const int hcol = h0 + wc * 64 + j * 16 + l15;
      const float bb = b2[e * HID + hcol];
#pragma unroll
      for (int rg = 0; rg < 4; rg++) {
        const int row = wr * 64 + i * 16 + q * 4 + rg;
        if (row < rows) {
          const size_t idx = (size_t)(off + ytile * 128 + row) * HID + hcol;
          const float g = acc[i][j][rg] + bb;
          const float h = bf2f(act[idx]);
          act[idx] = f2bf(h * (g / (1.f + __expf(-g))));
        }
      }
    }
}

// ---------------------------------------------------------------------------
// stage2 (store path): pair_out[pr] = (act @ W3 + b3) * wt  (bf16)
// grid (8, 64, 8), block 256. K = HID.
// ---------------------------------------------------------------------------
__global__ __launch_bounds__(256) void stage2s_kernel(
    const unsigned short* __restrict__ act, const unsigned short* __restrict__ w3bt,
    const float* __restrict__ b3, const float* __restrict__ pair_w,
    const int* __restrict__ ctrl, unsigned short* __restrict__ pair_out) {
  const int e = blockIdx.z;
  const int cnt = ctrl[e];
  const int ytile = blockIdx.y;
  if (ytile * 128 >= cnt) return;
  const int off = ctrl[8 + e];
  const int rows = min(128, cnt - ytile * 128);
  const int d0 = blockIdx.x * 128;
  const int rbase = off + ytile * 128;

  __shared__ unsigned short sA[128 * 64];
  __shared__ unsigned short sW[128 * 64];

  const int tid = threadIdx.x;
  const int wv = tid >> 6, lane = tid & 63;
  const int rr = tid >> 3;
  const int c8 = ((tid & 7) ^ (rr & 7)) * 8;
  const unsigned short* w3p = w3bt + (size_t)e * DIM * HID + (size_t)d0 * HID;
  const unsigned short* ga[4];
  const unsigned short* gw[4];
#pragma unroll
  for (int r = 0; r < 4; r++) {
    ga[r] = act + (size_t)(rbase + min(rr + r * 32, rows - 1)) * HID + c8;
    gw[r] = w3p + (size_t)(rr + r * 32) * HID + c8;
  }

  f32x4 acc[4][4];
#pragma unroll
  for (int i = 0; i < 4; i++)
#pragma unroll
    for (int j = 0; j < 4; j++) acc[i][j] = (f32x4){0.f, 0.f, 0.f, 0.f};

  const int wr = wv >> 1, wc = wv & 1;
  const int l15 = lane & 15, q = lane >> 4, r7 = lane & 7;

  for (int k0 = 0; k0 < HID; k0 += 64) {
#pragma unroll
    for (int r = 0; r < 4; r++) {
      async16(ga[r], sA + (r * 256 + wv * 64) * 8);
      async16(gw[r], sW + (r * 256 + wv * 64) * 8);
      ga[r] += 64; gw[r] += 64;
    }
    __syncthreads();
#pragma unroll
    for (int kk = 0; kk < 2; kk++) {
      const int pch = ((kk * 4 + q) ^ r7) * 8;
      bf16x8 af[4], bf[4];
#pragma unroll
      for (int i = 0; i < 4; i++)
        af[i] = *(const bf16x8*)(sA + (wr * 64 + i * 16 + l15) * 64 + pch);
#pragma unroll
      for (int j = 0; j < 4; j++)
        bf[j] = *(const bf16x8*)(sW + (wc * 64 + j * 16 + l15) * 64 + pch);
#pragma unroll
      for (int i = 0; i < 4; i++)
#pragma unroll
        for (int j = 0; j < 4; j++)
          acc[i][j] =
              __builtin_amdgcn_mfma_f32_16x16x32_bf16(af[i], bf[j], acc[i][j], 0, 0, 0);
    }
    __syncthreads();
  }

#pragma unroll
  for (int i = 0; i < 4; i++)
#pragma unroll
    for (int rg = 0; rg < 4; rg++) {
      const int row = wr * 64 + i * 16 + q * 4 + rg;
      if (row < rows) {
        const int pr = rbase + row;
        const float wt = pair_w[pr];
#pragma unroll
        for (int j = 0; j < 4; j++) {
          const int dcol = d0 + wc * 64 + j * 16 + l15;
          pair_out[(size_t)pr * DIM + dcol] = f2bf((acc[i][j][rg] + b3[e * DIM + dcol]) * wt);
        }
      }
    }
}

// ---------------------------------------------------------------------------
// stage2 (atomic fallback): out[tok] += (act @ W3 + b3) * wt
// ---------------------------------------------------------------------------
__global__ __launch_bounds__(256) void stage2a_kernel(
    const unsigned short* __restrict__ act, const unsigned short* __restrict__ w3bt,
    const float* __restrict__ b3, const int* __restrict__ tok_list,
    const float* __restrict__ pair_w, const int* __restrict__ ctrl,
    float* __restrict__ out) {
  const int e = blockIdx.z;
  const int cnt = ctrl[e];
  const int ytile = blockIdx.y;
  if (ytile * 128 >= cnt) return;
  const int off = ctrl[8 + e];
  const int rows = min(128, cnt - ytile * 128);
  const int d0 = blockIdx.x * 128;
  const int rbase = off + ytile * 128;

  __shared__ unsigned short sA[128 * 64];
  __shared__ unsigned short sW[128 * 64];

  const int tid = threadIdx.x;
  const int wv = tid >> 6, lane = tid & 63;
  const int rr = tid >> 3;
  const int c8 = ((tid & 7) ^ (rr & 7)) * 8;
  const unsigned short* w3p = w3bt + (size_t)e * DIM * HID + (size_t)d0 * HID;
  const unsigned short* ga[4];
  const unsigned short* gw[4];
#pragma unroll
  for (int r = 0; r < 4; r++) {
    ga[r] = act + (size_t)(rbase + min(rr + r * 32, rows - 1)) * HID + c8;
    gw[r] = w3p + (size_t)(rr + r * 32) * HID + c8;
  }

  f32x4 acc[4][4];
#pragma unroll
  for (int i = 0; i < 4; i++)
#pragma unroll
    for (int j = 0; j < 4; j++) acc[i][j] = (f32x4){0.f, 0.f, 0.f, 0.f};

  const int wr = wv >> 1, wc = wv & 1;
  const int l15 = lane & 15, q = lane >> 4, r7 = lane & 7;

  for (int k0 = 0; k0 < HID; k0 += 64) {
#pragma unroll
    for (int r = 0; r < 4; r++) {
      async16(ga[r], sA + (r * 256 + wv * 64) * 8);
      async16(gw[r], sW + (r * 256 + wv * 64) * 8);
      ga[r] += 64; gw[r] += 64;
    }
    __syncthreads();
#pragma unroll
    for (int kk = 0; kk < 2; kk++) {
      const int pch = ((kk * 4 + q) ^ r7) * 8;
      bf16x8 af[4], bf[4];
#pragma unroll
      for (int i = 0; i < 4; i++)
        af[i] = *(const bf16x8*)(sA + (wr * 64 + i * 16 + l15) * 64 + pch);
#pragma unroll
      for (int j = 0; j < 4; j++)
        bf[j] = *(const bf16x8*)(sW + (wc * 64 + j * 16 + l15) * 64 + pch);
#pragma unroll
      for (int i = 0; i < 4; i++)
#pragma unroll
        for (int j = 0; j < 4; j++)
          acc[i][j] =
              __builtin_amdgcn_mfma_f32_16x16x32_bf16(af[i], bf[j], acc[i][j], 0, 0, 0);
    }
    __syncthreads();
  }

#pragma unroll
  for (int i = 0; i < 4; i++)
#pragma unroll
    for (int rg = 0; rg < 4; rg++) {
      const int row = wr * 64 + i * 16 + q * 4 + rg;
      if (row < rows) {
        const int pr = rbase + row;
        const int tok = tok_list[pr];
        const float wt = pair_w[pr];
#pragma unroll
        for (int j = 0; j < 4; j++) {
          const int dcol = d0 + wc * 64 + j * 16 + l15;
          atomicAdd(out + (size_t)tok * DIM + dcol, (acc[i][j][rg] + b3[e * DIM + dcol]) * wt);
        }
      }
    }
}

// ---------------------------------------------------------------------------
// combine: out[t] = pair_out[pos(t,0)] + pair_out[pos(t,1)]. grid NTOK x 256.
// ---------------------------------------------------------------------------
__global__ __launch_bounds__(256) void combine_kernel(
    const unsigned short* __restrict__ pair_out, const int* __restrict__ pair_pos,
    float* __restrict__ out) {
  const int t = blockIdx.x;
  const int d = threadIdx.x * 4;
  const int p0 = pair_pos[t * 2], p1 = pair_pos[t * 2 + 1];
  const ushort4 a = *(const ushort4*)(pair_out + (size_t)p0 * DIM + d);
  const ushort4 b = *(const ushort4*)(pair_out + (size_t)p1 * DIM + d);
  float4 r;
  r.x = bf2f(a.x) + bf2f(b.x);
  r.y = bf2f(a.y) + bf2f(b.y);
  r.z = bf2f(a.z) + bf2f(b.z);
  r.w = bf2f(a.w) + bf2f(b.w);
  *(float4*)(out + (size_t)t * DIM + d) = r;
}

// ---------------------------------------------------------------------------
// workspace layout (bytes)
// ---------------------------------------------------------------------------
static const size_t SZ_XB  = (size_t)NTOK * DIM * 2;        // 16 MB
static const size_t SZ_W   = (size_t)NE * DIM * HID * 2;    // 32 MB each
static const size_t SZ_ACT = (size_t)NPAIR * HID * 2;       // 64 MB
static const size_t OFF_XB  = 0;
static const size_t OFF_W1  = OFF_XB + SZ_XB;
static const size_t OFF_W2  = OFF_W1 + SZ_W;
static const size_t OFF_W3  = OFF_W2 + SZ_W;
static const size_t OFF_ACT = OFF_W3 + SZ_W;
static const size_t OFF_SC  = OFF_ACT + SZ_ACT;
static const size_t OFF_RE  = OFF_SC + (size_t)NTOK * NE * 4;
static const size_t OFF_RW  = OFF_RE + (size_t)NPAIR * 4;
static const size_t OFF_TL  = OFF_RW + (size_t)NPAIR * 4;
static const size_t OFF_PW  = OFF_TL + (size_t)NPAIR * 4;
static const size_t OFF_PP  = OFF_PW + (size_t)NPAIR * 4;
static const size_t OFF_CT  = OFF_PP + (size_t)NPAIR * 4;
static const size_t WS_BASE = OFF_CT + 128;
static const size_t OFF_PO  = WS_BASE;                      // pair_out bf16, 32 MB
static const size_t WS_FULL = OFF_PO + (size_t)NPAIR * DIM * 2;

extern "C" void kernel_launch(void* const* d_in, const int* in_sizes, int n_in,
                              void* d_out, int out_size, void* d_ws, size_t ws_size,
                              hipStream_t stream) {
  const float* x      = (const float*)d_in[0];
  const float* gate_w = (const float*)d_in[1];
  const float* gate_b = (const float*)d_in[2];
  const float* w1     = (const float*)d_in[3];
  const float* b1     = (const float*)d_in[4];
  const float* w2     = (const float*)d_in[5];
  const float* b2     = (const float*)d_in[6];
  const float* w3     = (const float*)d_in[7];
  const float* b3     = (const float*)d_in[8];
  float* out = (float*)d_out;

  if (ws_size < WS_BASE) {
    fprintf(stderr, "kernel_launch: ws_size %zu < needed %zu\n", ws_size, WS_BASE);
    return;
  }
  const bool store_path = (ws_size >= WS_FULL);

  char* ws = (char*)d_ws;
  unsigned short* xb   = (unsigned short*)(ws + OFF_XB);
  unsigned short* w1bt = (unsigned short*)(ws + OFF_W1);
  unsigned short* w2bt = (unsigned short*)(ws + OFF_W2);
  unsigned short* w3bt = (unsigned short*)(ws + OFF_W3);
  unsigned short* act  = (unsigned short*)(ws + OFF_ACT);
  float* scores        = (float*)(ws + OFF_SC);
  int* route_e         = (int*)(ws + OFF_RE);
  float* route_w       = (float*)(ws + OFF_RW);
  int* tok_list        = (int*)(ws + OFF_TL);
  float* pair_w        = (float*)(ws + OFF_PW);
  int* pair_pos        = (int*)(ws + OFF_PP);
  int* ctrl            = (int*)(ws + OFF_CT);
  unsigned short* pout = (unsigned short*)(ws + OFF_PO);

  hipMemsetAsync(ctrl, 0, 128, stream);
  if (!store_path)
    hipMemsetAsync(d_out, 0, (size_t)out_size * sizeof(float), stream);

  prep_kernel<<<dim3(2048, 24), 256, 0, stream>>>(w1, w2, w3, w1bt, w2bt, w3bt);
  gate_kernel<<<2048, 256, 0, stream>>>(x, gate_w, gate_b, xb, scores, route_e,
                                        route_w, ctrl);
  finalize_kernel<<<1, 1024, 0, stream>>>(scores, ctrl, out + (out_size - 1));
  scatter_kernel<<<32, 256, 0, stream>>>(route_e, route_w, ctrl, tok_list, pair_w,
                                         pair_pos);
  stage1a_kernel<<<dim3(16, 64, 8), 256, 0, stream>>>(xb, w1bt, b1, tok_list, ctrl, act);
  stage1b_kernel<<<dim3(16, 64, 8), 256, 0, stream>>>(xb, w2bt, b2, tok_list, ctrl, act);
  if (store_path) {
    stage2s_kernel<<<dim3(8, 64, 8), 256, 0, stream>>>(act, w3bt, b3, pair_w, ctrl, pout);
    combine_kernel<<<NTOK, 256, 0, stream>>>(pout, pair_pos, out);
  } else {
    stage2a_kernel<<<dim3(8, 64, 8), 256, 0, stream>>>(act, w3bt, b3, tok_list,
                                                       pair_w, ctrl, out);
  }
}

// Round 5
// 787.748 us; speedup vs baseline: 1.3709x; 1.2257x over previous
//
#include <hip/hip_runtime.h>
#include <cstdio>

#define NTOK 8192
#define DIM 1024
#define HID 2048
#define NE 8
#define NPAIR (NTOK * 2)

typedef __attribute__((ext_vector_type(8))) short bf16x8;
typedef __attribute__((ext_vector_type(4))) float f32x4;

typedef const __attribute__((address_space(1))) void* gas_ptr;
typedef __attribute__((address_space(3))) void* las_ptr;

__device__ __forceinline__ void async16(const void* g, void* s) {
  // direct global->LDS, 16B per lane; LDS dest = wave-uniform base + lane*16
  __builtin_amdgcn_global_load_lds((gas_ptr)g, (las_ptr)s, 16, 0, 0);
}

__device__ __forceinline__ unsigned short f2bf(float f) {
  unsigned int u = __float_as_uint(f);
  u = (u + 0x7fff + ((u >> 16) & 1)) >> 16;  // RNE
  return (unsigned short)u;
}

__device__ __forceinline__ float bf2f(unsigned short u) {
  return __uint_as_float((unsigned int)u << 16);
}

// GEMM LDS tiles are [row][64 bf16] = 128B rows. Physical 16B-chunk of (row r,
// logical chunk c) is c ^ (r&7) -> fragment reads spread across all 8 bank
// groups (2-way aliasing only, free on gfx950). Staging lane loads global
// chunk (slot&7)^(row&7) since its LDS slot chunk is fixed.
// All GEMMs: 128x128 tile, BK=64, 2x2 waves, single 4x4 f32x4 acc per wave
// (64 acc regs -> ~164 total, no spill; r3's dual-acc 128-reg tile spilled).

// ---------------------------------------------------------------------------
// prep: w1[e][d][h] -> w1bt[e][h][d] (bf16), w2 same, w3[e][h][d] -> w3bt[e][d][h]
// ---------------------------------------------------------------------------
__global__ __launch_bounds__(256) void prep_kernel(
    const float* __restrict__ w1, const float* __restrict__ w2,
    const float* __restrict__ w3, unsigned short* __restrict__ w1bt,
    unsigned short* __restrict__ w2bt, unsigned short* __restrict__ w3bt) {
  const int z = blockIdx.y;
  const int m = z >> 3, e = z & 7;
  int R, C;
  const float* in;
  unsigned short* outp;
  if (m == 0)      { R = DIM; C = HID; in = w1; outp = w1bt; }
  else if (m == 1) { R = DIM; C = HID; in = w2; outp = w2bt; }
  else             { R = HID; C = DIM; in = w3; outp = w3bt; }
  in += (size_t)e * DIM * HID;
  outp += (size_t)e * DIM * HID;

  const int tilesx = C >> 5;
  const int c0 = (blockIdx.x % tilesx) * 32;
  const int r0 = (blockIdx.x / tilesx) * 32;

  __shared__ float tile[32][33];
  const int c = threadIdx.x & 31, rr = threadIdx.x >> 5;
#pragma unroll
  for (int i = 0; i < 4; i++) {
    const int r = rr + i * 8;
    tile[r][c] = in[(size_t)(r0 + r) * C + c0 + c];
  }
  __syncthreads();
#pragma unroll
  for (int i = 0; i < 4; i++) {
    const int cc2 = rr + i * 8;  // column of original = row of output
    outp[(size_t)(c0 + cc2) * R + r0 + c] = f2bf(tile[c][cc2]);
  }
}

// ---------------------------------------------------------------------------
// gating: 1 wave per token. Transposed gate_w in LDS -> conflict-free b128
// reads (r4's [d][e] layout put all 64 lanes on one bank: 64-way conflict,
// ~200us of LDS-port serialization). No atomics here (counts in finalize).
// ---------------------------------------------------------------------------
__global__ __launch_bounds__(256) void gate_kernel(
    const float* __restrict__ x, const float* __restrict__ gw,
    const float* __restrict__ gb, unsigned short* __restrict__ xb,
    float* __restrict__ scores, int* __restrict__ route_e,
    float* __restrict__ route_w) {
  __shared__ float sgwT[NE][DIM];  // 32 KB, transposed [e][d]
  const int tid = threadIdx.x;
#pragma unroll
  for (int i = 0; i < 8; i++) {
    const int j = i * 256 + tid;               // float4 index into gw[DIM][NE]
    const float4 v = ((const float4*)gw)[j];
    const int d = j >> 1, e0 = (j & 1) * 4;    // 2-way bank alias on store: free
    sgwT[e0 + 0][d] = v.x; sgwT[e0 + 1][d] = v.y;
    sgwT[e0 + 2][d] = v.z; sgwT[e0 + 3][d] = v.w;
  }
  __syncthreads();

  const int wv = tid >> 6, lane = tid & 63;
  const int t = blockIdx.x * 4 + wv;
  float acc[NE] = {0.f, 0.f, 0.f, 0.f, 0.f, 0.f, 0.f, 0.f};
  const float4* x4 = (const float4*)(x + (size_t)t * DIM);
#pragma unroll
  for (int i = 0; i < 4; i++) {
    const float4 xv = x4[i * 64 + lane];
    const int d4 = i * 64 + lane;              // float4 index; byte addr lane*16
    ushort4 xbv;
    xbv.x = f2bf(xv.x); xbv.y = f2bf(xv.y);
    xbv.z = f2bf(xv.z); xbv.w = f2bf(xv.w);
    *(ushort4*)(xb + (size_t)t * DIM + d4 * 4) = xbv;
#pragma unroll
    for (int e = 0; e < NE; e++) {
      const float4 wv4 = *(const float4*)&sgwT[e][d4 * 4];  // ds_read_b128, no conflict
      acc[e] += xv.x * wv4.x + xv.y * wv4.y + xv.z * wv4.z + xv.w * wv4.w;
    }
  }
#pragma unroll
  for (int e = 0; e < NE; e++)
#pragma unroll
    for (int s = 32; s; s >>= 1) acc[e] += __shfl_xor(acc[e], s, 64);

  if (lane == 0) {
    float l[NE], m = -1e30f;
#pragma unroll
    for (int e = 0; e < NE; e++) { l[e] = acc[e] + gb[e]; m = fmaxf(m, l[e]); }
    float p[NE], sum = 0.f;
#pragma unroll
    for (int e = 0; e < NE; e++) { p[e] = __expf(l[e] - m); sum += p[e]; }
    const float inv = 1.f / sum;
    float s[NE];
#pragma unroll
    for (int e = 0; e < NE; e++) { s[e] = p[e] * inv; scores[t * NE + e] = s[e]; }
    int i1 = 0;
    for (int e = 1; e < NE; e++) if (s[e] > s[i1]) i1 = e;
    int i2 = -1;
    for (int e = 0; e < NE; e++) {
      if (e == i1) continue;
      if (i2 < 0 || s[e] > s[i2]) i2 = e;
    }
    route_e[t * 2] = i1; route_e[t * 2 + 1] = i2;
    route_w[t * 2] = s[i1]; route_w[t * 2 + 1] = s[i2];
  }
}

// ---------------------------------------------------------------------------
// finalize: usage -> lb_loss (d_out tail); counts via route_e histogram;
// prefix offsets; cursors. Writes every ctrl field (no memset needed).
// ---------------------------------------------------------------------------
__global__ void finalize_kernel(const float* __restrict__ scores,
                                const int* __restrict__ route_e,
                                int* __restrict__ ctrl,
                                float* __restrict__ out_lb) {
  __shared__ float red[1024];
  __shared__ int hist[NE];
  const int tid = threadIdx.x;
  if (tid < NE) hist[tid] = 0;
  const int e = tid & 7, row = tid >> 3;
  float s = 0.f;
  for (int i = 0; i < 64; i++) s += scores[(size_t)(row + i * 128) * NE + e];
  red[tid] = s;
  __syncthreads();  // hist zero + red visible
#pragma unroll
  for (int i = 0; i < 16; i++)
    atomicAdd(&hist[route_e[i * 1024 + tid]], 1);
  for (int st = 512; st >= 8; st >>= 1) {
    __syncthreads();
    if (tid < st) red[tid] += red[tid + st];
  }
  __syncthreads();
  if (tid == 0) {
    float lb = 0.f;
    for (int ee = 0; ee < NE; ee++) {
      const float u = red[ee] * (1.f / 8192.f);
      lb -= u * __logf(u + 1e-9f);
    }
    *out_lb = lb;
    int o = 0;
    for (int ee = 0; ee < NE; ee++) {
      ctrl[ee] = hist[ee];    // counts
      ctrl[8 + ee] = o;       // offsets
      ctrl[17 + ee] = o;      // cursors
      o += hist[ee];
    }
    ctrl[16] = o;
  }
}

// ---------------------------------------------------------------------------
// scatter: build per-expert compacted token lists + inverse map pair_pos
// ---------------------------------------------------------------------------
__global__ void scatter_kernel(const int* __restrict__ route_e,
                               const float* __restrict__ route_w,
                               int* __restrict__ ctrl,
                               int* __restrict__ tok_list,
                               float* __restrict__ pair_w,
                               int* __restrict__ pair_pos) {
  const int t = blockIdx.x * 256 + threadIdx.x;
  if (t >= NTOK) return;
#pragma unroll
  for (int k = 0; k < 2; k++) {
    const int e = route_e[t * 2 + k];
    const int p = atomicAdd(&ctrl[17 + e], 1);
    tok_list[p] = t;
    pair_w[p] = route_w[t * 2 + k] * 0.70710678118654752f;  // comb * 1/sqrt(2)
    pair_pos[t * 2 + k] = p;
  }
}

// ---------------------------------------------------------------------------
// stage1a: h = X@W1 + b1 for routed rows -> act (bf16)
// grid (16, 64, 8), block 256. 128x128 tile, BK=64, 2x2 waves, single acc.
// ---------------------------------------------------------------------------
__global__ __launch_bounds__(256) void stage1a_kernel(
    const unsigned short* __restrict__ xb, const unsigned short* __restrict__ wbt,
    const float* __restrict__ b1, const int* __restrict__ tok_list,
    const int* __restrict__ ctrl, unsigned short* __restrict__ act) {
  const int e = blockIdx.z;
  const int cnt = ctrl[e];
  const int ytile = blockIdx.y;
  if (ytile * 128 >= cnt) return;
  const int off = ctrl[8 + e];
  const int rows = min(128, cnt - ytile * 128);
  const int h0 = blockIdx.x * 128;

  __shared__ unsigned short sX[128 * 64];
  __shared__ unsigned short sW[128 * 64];
  __shared__ int stok[128];

  const int tid = threadIdx.x;
  const int wv = tid >> 6, lane = tid & 63;

  if (tid < 128) stok[tid] = tok_list[off + ytile * 128 + min(tid, rows - 1)];
  __syncthreads();

  const int rr = tid >> 3;
  const int c8 = ((tid & 7) ^ (rr & 7)) * 8;  // swizzled chunk offset (shorts)
  const unsigned short* wp = wbt + (size_t)e * HID * DIM + (size_t)h0 * DIM;
  const unsigned short* gx[4];
  const unsigned short* gw[4];
#pragma unroll
  for (int r = 0; r < 4; r++) {
    gx[r] = xb + (size_t)stok[rr + r * 32] * DIM + c8;
    gw[r] = wp + (size_t)(rr + r * 32) * DIM + c8;
  }

  f32x4 acc[4][4];
#pragma unroll
  for (int i = 0; i < 4; i++)
#pragma unroll
    for (int j = 0; j < 4; j++) acc[i][j] = (f32x4){0.f, 0.f, 0.f, 0.f};

  const int wr = wv >> 1, wc = wv & 1;
  const int l15 = lane & 15, q = lane >> 4, r7 = lane & 7;

  for (int k0 = 0; k0 < DIM; k0 += 64) {
#pragma unroll
    for (int r = 0; r < 4; r++) {
      async16(gx[r], sX + (r * 256 + wv * 64) * 8);
      async16(gw[r], sW + (r * 256 + wv * 64) * 8);
      gx[r] += 64; gw[r] += 64;
    }
    __syncthreads();
#pragma unroll
    for (int kk = 0; kk < 2; kk++) {
      const int pch = ((kk * 4 + q) ^ r7) * 8;
      bf16x8 af[4], bf[4];
#pragma unroll
      for (int i = 0; i < 4; i++)
        af[i] = *(const bf16x8*)(sX + (wr * 64 + i * 16 + l15) * 64 + pch);
#pragma unroll
      for (int j = 0; j < 4; j++)
        bf[j] = *(const bf16x8*)(sW + (wc * 64 + j * 16 + l15) * 64 + pch);
#pragma unroll
      for (int i = 0; i < 4; i++)
#pragma unroll
        for (int j = 0; j < 4; j++)
          acc[i][j] =
              __builtin_amdgcn_mfma_f32_16x16x32_bf16(af[i], bf[j], acc[i][j], 0, 0, 0);
    }
    __syncthreads();
  }

#pragma unroll
  for (int i = 0; i < 4; i++)
#pragma unroll
    for (int j = 0; j < 4; j++) {
      const int hcol = h0 + wc * 64 + j * 16 + l15;
      const float bb = b1[e * HID + hcol];
#pragma unroll
      for (int rg = 0; rg < 4; rg++) {
        const int row = wr * 64 + i * 16 + q * 4 + rg;
        if (row < rows)
          act[(size_t)(off + ytile * 128 + row) * HID + hcol] = f2bf(acc[i][j][rg] + bb);
      }
    }
}

// ---------------------------------------------------------------------------
// stage1b: g = X@W2 + b2; act *= in-place: act = h * silu(g)
// ---------------------------------------------------------------------------
__global__ __launch_bounds__(256) void stage1b_kernel(
    const unsigned short* __restrict__ xb, const unsigned short* __restrict__ wbt,
    const float* __restrict__ b2, const int* __restrict__ tok_list,
    const int* __restrict__ ctrl, unsigned short* __restrict__ act) {
  const int e = blockIdx.z;
  const int cnt = ctrl[e];
  const int ytile = blockIdx.y;
  if (ytile * 128 >= cnt) return;
  const int off = ctrl[8 + e];
  const int rows = min(128, cnt - ytile * 128);
  const int h0 = blockIdx.x * 128;

  __shared__ unsigned short sX[128 * 64];
  __shared__ unsigned short sW[128 * 64];
  __shared__ int stok[128];

  const int tid = threadIdx.x;
  const int wv = tid >> 6, lane = tid & 63;

  if (tid < 128) stok[tid] = tok_list[off + ytile * 128 + min(tid, rows - 1)];
  __syncthreads();

  const int rr = tid >> 3;
  const int c8 = ((tid & 7) ^ (rr & 7)) * 8;
  const unsigned short* wp = wbt + (size_t)e * HID * DIM + (size_t)h0 * DIM;
  const unsigned short* gx[4];
  const unsigned short* gw[4];
#pragma unroll
  for (int r = 0; r < 4; r++) {
    gx[r] = xb + (size_t)stok[rr + r * 32] * DIM + c8;
    gw[r] = wp + (size_t)(rr + r * 32) * DIM + c8;
  }

  f32x4 acc[4][4];
#pragma unroll
  for (int i = 0; i < 4; i++)
#pragma unroll
    for (int j = 0; j < 4; j++) acc[i][j] = (f32x4){0.f, 0.f, 0.f, 0.f};

  const int wr = wv >> 1, wc = wv & 1;
  const int l15 = lane & 15, q = lane >> 4, r7 = lane & 7;

  for (int k0 = 0; k0 < DIM; k0 += 64) {
#pragma unroll
    for (int r = 0; r < 4; r++) {
      async16(gx[r], sX + (r * 256 + wv * 64) * 8);
      async16(gw[r], sW + (r * 256 + wv * 64) * 8);
      gx[r] += 64; gw[r] += 64;
    }
    __syncthreads();
#pragma unroll
    for (int kk = 0; kk < 2; kk++) {
      const int pch = ((kk * 4 + q) ^ r7) * 8;
      bf16x8 af[4], bf[4];
#pragma unroll
      for (int i = 0; i < 4; i++)
        af[i] = *(const bf16x8*)(sX + (wr * 64 + i * 16 + l15) * 64 + pch);
#pragma unroll
      for (int j = 0; j < 4; j++)
        bf[j] = *(const bf16x8*)(sW + (wc * 64 + j * 16 + l15) * 64 + pch);
#pragma unroll
      for (int i = 0; i < 4; i++)
#pragma unroll
        for (int j = 0; j < 4; j++)
          acc[i][j] =
              __builtin_amdgcn_mfma_f32_16x16x32_bf16(af[i], bf[j], acc[i][j], 0, 0, 0);
    }
    __syncthreads();
  }

#pragma unroll
  for (int i = 0; i < 4; i++)
#pragma unroll
    for (int j = 0; j < 4; j++) {
      const int hcol = h0 + wc * 64 + j * 16 + l15;
      const float bb = b2[e * HID + hcol];
#pragma unroll
      for (int rg = 0; rg < 4; rg++) {
        const int row = wr * 64 + i * 16 + q * 4 + rg;
        if (row < rows) {
          const size_t idx = (size_t)(off + ytile * 128 + row) * HID + hcol;
          const float g = acc[i][j][rg] + bb;
          const float h = bf2f(act[idx]);
          act[idx] = f2bf(h * (g / (1.f + __expf(-g))));
        }
      }
    }
}

// ---------------------------------------------------------------------------
// stage2 (store path): pair_out[pr] = (act @ W3 + b3) * wt  (bf16)
// grid (8, 64, 8), block 256. K = HID.
// ---------------------------------------------------------------------------
__global__ __launch_bounds__(256) void stage2s_kernel(
    const unsigned short* __restrict__ act, const unsigned short* __restrict__ w3bt,
    const float* __restrict__ b3, const float* __restrict__ pair_w,
    const int* __restrict__ ctrl, unsigned short* __restrict__ pair_out) {
  const int e = blockIdx.z;
  const int cnt = ctrl[e];
  const int ytile = blockIdx.y;
  if (ytile * 128 >= cnt) return;
  const int off = ctrl[8 + e];
  const int rows = min(128, cnt - ytile * 128);
  const int d0 = blockIdx.x * 128;
  const int rbase = off + ytile * 128;

  __shared__ unsigned short sA[128 * 64];
  __shared__ unsigned short sW[128 * 64];

  const int tid = threadIdx.x;
  const int wv = tid >> 6, lane = tid & 63;
  const int rr = tid >> 3;
  const int c8 = ((tid & 7) ^ (rr & 7)) * 8;
  const unsigned short* w3p = w3bt + (size_t)e * DIM * HID + (size_t)d0 * HID;
  const unsigned short* ga[4];
  const unsigned short* gw[4];
#pragma unroll
  for (int r = 0; r < 4; r++) {
    ga[r] = act + (size_t)(rbase + min(rr + r * 32, rows - 1)) * HID + c8;
    gw[r] = w3p + (size_t)(rr + r * 32) * HID + c8;
  }

  f32x4 acc[4][4];
#pragma unroll
  for (int i = 0; i < 4; i++)
#pragma unroll
    for (int j = 0; j < 4; j++) acc[i][j] = (f32x4){0.f, 0.f, 0.f, 0.f};

  const int wr = wv >> 1, wc = wv & 1;
  const int l15 = lane & 15, q = lane >> 4, r7 = lane & 7;

  for (int k0 = 0; k0 < HID; k0 += 64) {
#pragma unroll
    for (int r = 0; r < 4; r++) {
      async16(ga[r], sA + (r * 256 + wv * 64) * 8);
      async16(gw[r], sW + (r * 256 + wv * 64) * 8);
      ga[r] += 64; gw[r] += 64;
    }
    __syncthreads();
#pragma unroll
    for (int kk = 0; kk < 2; kk++) {
      const int pch = ((kk * 4 + q) ^ r7) * 8;
      bf16x8 af[4], bf[4];
#pragma unroll
      for (int i = 0; i < 4; i++)
        af[i] = *(const bf16x8*)(sA + (wr * 64 + i * 16 + l15) * 64 + pch);
#pragma unroll
      for (int j = 0; j < 4; j++)
        bf[j] = *(const bf16x8*)(sW + (wc * 64 + j * 16 + l15) * 64 + pch);
#pragma unroll
      for (int i = 0; i < 4; i++)
#pragma unroll
        for (int j = 0; j < 4; j++)
          acc[i][j] =
              __builtin_amdgcn_mfma_f32_16x16x32_bf16(af[i], bf[j], acc[i][j], 0, 0, 0);
    }
    __syncthreads();
  }

#pragma unroll
  for (int i = 0; i < 4; i++)
#pragma unroll
    for (int rg = 0; rg < 4; rg++) {
      const int row = wr * 64 + i * 16 + q * 4 + rg;
      if (row < rows) {
        const int pr = rbase + row;
        const float wt = pair_w[pr];
#pragma unroll
        for (int j = 0; j < 4; j++) {
          const int dcol = d0 + wc * 64 + j * 16 + l15;
          pair_out[(size_t)pr * DIM + dcol] = f2bf((acc[i][j][rg] + b3[e * DIM + dcol]) * wt);
        }
      }
    }
}

// ---------------------------------------------------------------------------
// stage2 (atomic fallback): out[tok] += (act @ W3 + b3) * wt
// ---------------------------------------------------------------------------
__global__ __launch_bounds__(256) void stage2a_kernel(
    const unsigned short* __restrict__ act, const unsigned short* __restrict__ w3bt,
    const float* __restrict__ b3, const int* __restrict__ tok_list,
    const float* __restrict__ pair_w, const int* __restrict__ ctrl,
    float* __restrict__ out) {
  const int e = blockIdx.z;
  const int cnt = ctrl[e];
  const int ytile = blockIdx.y;
  if (ytile * 128 >= cnt) return;
  const int off = ctrl[8 + e];
  const int rows = min(128, cnt - ytile * 128);
  const int d0 = blockIdx.x * 128;
  const int rbase = off + ytile * 128;

  __shared__ unsigned short sA[128 * 64];
  __shared__ unsigned short sW[128 * 64];

  const int tid = threadIdx.x;
  const int wv = tid >> 6, lane = tid & 63;
  const int rr = tid >> 3;
  const int c8 = ((tid & 7) ^ (rr & 7)) * 8;
  const unsigned short* w3p = w3bt + (size_t)e * DIM * HID + (size_t)d0 * HID;
  const unsigned short* ga[4];
  const unsigned short* gw[4];
#pragma unroll
  for (int r = 0; r < 4; r++) {
    ga[r] = act + (size_t)(rbase + min(rr + r * 32, rows - 1)) * HID + c8;
    gw[r] = w3p + (size_t)(rr + r * 32) * HID + c8;
  }

  f32x4 acc[4][4];
#pragma unroll
  for (int i = 0; i < 4; i++)
#pragma unroll
    for (int j = 0; j < 4; j++) acc[i][j] = (f32x4){0.f, 0.f, 0.f, 0.f};

  const int wr = wv >> 1, wc = wv & 1;
  const int l15 = lane & 15, q = lane >> 4, r7 = lane & 7;

  for (int k0 = 0; k0 < HID; k0 += 64) {
#pragma unroll
    for (int r = 0; r < 4; r++) {
      async16(ga[r], sA + (r * 256 + wv * 64) * 8);
      async16(gw[r], sW + (r * 256 + wv * 64) * 8);
      ga[r] += 64; gw[r] += 64;
    }
    __syncthreads();
#pragma unroll
    for (int kk = 0; kk < 2; kk++) {
      const int pch = ((kk * 4 + q) ^ r7) * 8;
      bf16x8 af[4], bf[4];
#pragma unroll
      for (int i = 0; i < 4; i++)
        af[i] = *(const bf16x8*)(sA + (wr * 64 + i * 16 + l15) * 64 + pch);
#pragma unroll
      for (int j = 0; j < 4; j++)
        bf[j] = *(const bf16x8*)(sW + (wc * 64 + j * 16 + l15) * 64 + pch);
#pragma unroll
      for (int i = 0; i < 4; i++)
#pragma unroll
        for (int j = 0; j < 4; j++)
          acc[i][j] =
              __builtin_amdgcn_mfma_f32_16x16x32_bf16(af[i], bf[j], acc[i][j], 0, 0, 0);
    }
    __syncthreads();
  }

#pragma unroll
  for (int i = 0; i < 4; i++)
#pragma unroll
    for (int rg = 0; rg < 4; rg++) {
      const int row = wr * 64 + i * 16 + q * 4 + rg;
      if (row < rows) {
        const int pr = rbase + row;
        const int tok = tok_list[pr];
        const float wt = pair_w[pr];
#pragma unroll
        for (int j = 0; j < 4; j++) {
          const int dcol = d0 + wc * 64 + j * 16 + l15;
          atomicAdd(out + (size_t)tok * DIM + dcol, (acc[i][j][rg] + b3[e * DIM + dcol]) * wt);
        }
      }
    }
}

// ---------------------------------------------------------------------------
// combine: out[t] = pair_out[pos(t,0)] + pair_out[pos(t,1)]. grid NTOK x 256.
// ---------------------------------------------------------------------------
__global__ __launch_bounds__(256) void combine_kernel(
    const unsigned short* __restrict__ pair_out, const int* __restrict__ pair_pos,
    float* __restrict__ out) {
  const int t = blockIdx.x;
  const int d = threadIdx.x * 4;
  const int p0 = pair_pos[t * 2], p1 = pair_pos[t * 2 + 1];
  const ushort4 a = *(const ushort4*)(pair_out + (size_t)p0 * DIM + d);
  const ushort4 b = *(const ushort4*)(pair_out + (size_t)p1 * DIM + d);
  float4 r;
  r.x = bf2f(a.x) + bf2f(b.x);
  r.y = bf2f(a.y) + bf2f(b.y);
  r.z = bf2f(a.z) + bf2f(b.z);
  r.w = bf2f(a.w) + bf2f(b.w);
  *(float4*)(out + (size_t)t * DIM + d) = r;
}

// ---------------------------------------------------------------------------
// workspace layout (bytes)
// ---------------------------------------------------------------------------
static const size_t SZ_XB  = (size_t)NTOK * DIM * 2;        // 16 MB
static const size_t SZ_W   = (size_t)NE * DIM * HID * 2;    // 32 MB each
static const size_t SZ_ACT = (size_t)NPAIR * HID * 2;       // 64 MB
static const size_t OFF_XB  = 0;
static const size_t OFF_W1  = OFF_XB + SZ_XB;
static const size_t OFF_W2  = OFF_W1 + SZ_W;
static const size_t OFF_W3  = OFF_W2 + SZ_W;
static const size_t OFF_ACT = OFF_W3 + SZ_W;
static const size_t OFF_SC  = OFF_ACT + SZ_ACT;
static const size_t OFF_RE  = OFF_SC + (size_t)NTOK * NE * 4;
static const size_t OFF_RW  = OFF_RE + (size_t)NPAIR * 4;
static const size_t OFF_TL  = OFF_RW + (size_t)NPAIR * 4;
static const size_t OFF_PW  = OFF_TL + (size_t)NPAIR * 4;
static const size_t OFF_PP  = OFF_PW + (size_t)NPAIR * 4;
static const size_t OFF_CT  = OFF_PP + (size_t)NPAIR * 4;
static const size_t WS_BASE = OFF_CT + 128;
static const size_t OFF_PO  = WS_BASE;                      // pair_out bf16, 32 MB
static const size_t WS_FULL = OFF_PO + (size_t)NPAIR * DIM * 2;

extern "C" void kernel_launch(void* const* d_in, const int* in_sizes, int n_in,
                              void* d_out, int out_size, void* d_ws, size_t ws_size,
                              hipStream_t stream) {
  const float* x      = (const float*)d_in[0];
  const float* gate_w = (const float*)d_in[1];
  const float* gate_b = (const float*)d_in[2];
  const float* w1     = (const float*)d_in[3];
  const float* b1     = (const float*)d_in[4];
  const float* w2     = (const float*)d_in[5];
  const float* b2     = (const float*)d_in[6];
  const float* w3     = (const float*)d_in[7];
  const float* b3     = (const float*)d_in[8];
  float* out = (float*)d_out;

  if (ws_size < WS_BASE) {
    fprintf(stderr, "kernel_launch: ws_size %zu < needed %zu\n", ws_size, WS_BASE);
    return;
  }
  const bool store_path = (ws_size >= WS_FULL);

  char* ws = (char*)d_ws;
  unsigned short* xb   = (unsigned short*)(ws + OFF_XB);
  unsigned short* w1bt = (unsigned short*)(ws + OFF_W1);
  unsigned short* w2bt = (unsigned short*)(ws + OFF_W2);
  unsigned short* w3bt = (unsigned short*)(ws + OFF_W3);
  unsigned short* act  = (unsigned short*)(ws + OFF_ACT);
  float* scores        = (float*)(ws + OFF_SC);
  int* route_e         = (int*)(ws + OFF_RE);
  float* route_w       = (float*)(ws + OFF_RW);
  int* tok_list        = (int*)(ws + OFF_TL);
  float* pair_w        = (float*)(ws + OFF_PW);
  int* pair_pos        = (int*)(ws + OFF_PP);
  int* ctrl            = (int*)(ws + OFF_CT);
  unsigned short* pout = (unsigned short*)(ws + OFF_PO);

  if (!store_path)
    hipMemsetAsync(d_out, 0, (size_t)out_size * sizeof(float), stream);

  prep_kernel<<<dim3(2048, 24), 256, 0, stream>>>(w1, w2, w3, w1bt, w2bt, w3bt);
  gate_kernel<<<2048, 256, 0, stream>>>(x, gate_w, gate_b, xb, scores, route_e,
                                        route_w);
  finalize_kernel<<<1, 1024, 0, stream>>>(scores, route_e, ctrl, out + (out_size - 1));
  scatter_kernel<<<32, 256, 0, stream>>>(route_e, route_w, ctrl, tok_list, pair_w,
                                         pair_pos);
  stage1a_kernel<<<dim3(16, 64, 8), 256, 0, stream>>>(xb, w1bt, b1, tok_list, ctrl, act);
  stage1b_kernel<<<dim3(16, 64, 8), 256, 0, stream>>>(xb, w2bt, b2, tok_list, ctrl, act);
  if (store_path) {
    stage2s_kernel<<<dim3(8, 64, 8), 256, 0, stream>>>(act, w3bt, b3, pair_w, ctrl, pout);
    combine_kernel<<<NTOK, 256, 0, stream>>>(pout, pair_pos, out);
  } else {
    stage2a_kernel<<<dim3(8, 64, 8), 256, 0, stream>>>(act, w3bt, b3, tok_list,
                                                       pair_w, ctrl, out);
  }
}